// Round 1
// baseline (1970.758 us; speedup 1.0000x reference)
//
#include <hip/hip_runtime.h>
#include <hip/hip_bf16.h>

using bf16 = __hip_bfloat16;

static constexpr int Bb = 16, Ss = 1024, Hh = 768;
static constexpr int MTOK = Bb * Ss; // 16384

// ---------- helpers ----------
__device__ inline float bf2f_us(unsigned short u) {
    return __uint_as_float(((unsigned)u) << 16);
}
__device__ inline unsigned short f2bu(float f) {
    unsigned u = __float_as_uint(f);
    unsigned r = u + 0x7fffu + ((u >> 16) & 1u);  // RNE
    return (unsigned short)(r >> 16);
}

__device__ inline float4 ld4(const float* p) { return *(const float4*)p; }
__device__ inline float4 ld4(const bf16* p) {
    ushort4 u = *(const ushort4*)p;
    float4 r;
    r.x = bf2f_us(u.x); r.y = bf2f_us(u.y); r.z = bf2f_us(u.z); r.w = bf2f_us(u.w);
    return r;
}

enum { EPI_B16 = 0, EPI_BIAS_B16 = 1, EPI_RELU_BIAS_B16 = 2, EPI_SCORE = 3, EPI_FINAL = 4 };

// C[m,n] = epi( sum_k A[m,k] * B'[k,n] ),  B' = B^T (TB=true, B is [N,K]) or B (TB=false, B is [K,N])
// fp32 accumulate; A/B element types templated; batch via blockIdx.z with strides.
template <typename AT, typename BT, int EPI, bool TB>
__global__ __launch_bounds__(256) void gemm_tiled(
    const AT* __restrict__ A, const BT* __restrict__ B,
    const float* __restrict__ bias, const bf16* __restrict__ resid,
    const int* __restrict__ mask, void* __restrict__ Cout,
    int M, int N, int K, int lda, int ldb, int ldc,
    long sAb, long sBb, long sCb, float scale)
{
    constexpr int BM = 64, BN = 64, BK = 16;
    __shared__ float As[BK][BM + 4];
    __shared__ float Bs[BK][BN + 4];

    const int tid = threadIdx.x;
    const int tx = tid & 15, ty = tid >> 4;
    const int m0 = blockIdx.y * BM, n0 = blockIdx.x * BN;
    const int bz = blockIdx.z;

    const AT* Ab = A + (long)bz * sAb;
    const BT* Bp = B + (long)bz * sBb;

    const int lrow = tid >> 2;          // 0..63
    const int lcol = (tid & 3) << 2;    // 0,4,8,12

    float acc[4][4];
#pragma unroll
    for (int i = 0; i < 4; i++)
#pragma unroll
        for (int j = 0; j < 4; j++) acc[i][j] = 0.f;

    for (int k0 = 0; k0 < K; k0 += BK) {
        // stage A tile transposed: As[k][m]
        {
            float4 av = ld4(Ab + (long)(m0 + lrow) * lda + (k0 + lcol));
            As[lcol + 0][lrow] = av.x;
            As[lcol + 1][lrow] = av.y;
            As[lcol + 2][lrow] = av.z;
            As[lcol + 3][lrow] = av.w;
        }
        if constexpr (TB) {
            // B is [N,K]: stage transposed so Bs[k][n]
            float4 bv = ld4(Bp + (long)(n0 + lrow) * ldb + (k0 + lcol));
            Bs[lcol + 0][lrow] = bv.x;
            Bs[lcol + 1][lrow] = bv.y;
            Bs[lcol + 2][lrow] = bv.z;
            Bs[lcol + 3][lrow] = bv.w;
        } else {
            // B is [K,N]: stage direct Bs[k][n]
            const int kr = tid >> 4;         // 0..15
            const int nc = (tid & 15) << 2;  // 0..60
            float4 bv = ld4(Bp + (long)(k0 + kr) * ldb + (n0 + nc));
            *(float4*)&Bs[kr][nc] = bv;
        }
        __syncthreads();
#pragma unroll
        for (int kk = 0; kk < BK; kk++) {
            float4 a = *(const float4*)&As[kk][ty << 2];
            float4 b = *(const float4*)&Bs[kk][tx << 2];
            float a4[4] = {a.x, a.y, a.z, a.w};
            float b4[4] = {b.x, b.y, b.z, b.w};
#pragma unroll
            for (int i = 0; i < 4; i++)
#pragma unroll
                for (int j = 0; j < 4; j++)
                    acc[i][j] = fmaf(a4[i], b4[j], acc[i][j]);
        }
        __syncthreads();
    }

    const int mr = m0 + (ty << 2);
    const int nc = n0 + (tx << 2);

    if constexpr (EPI == EPI_SCORE) {
        float* C = (float*)Cout + (long)bz * sCb;
        const int* mb = mask + bz * Ss;
        const int mt0 = mb[nc + 0], mt1 = mb[nc + 1], mt2 = mb[nc + 2], mt3 = mb[nc + 3];
#pragma unroll
        for (int i = 0; i < 4; i++) {
            const int ms = mb[mr + i];
            float4 o;
            o.x = acc[i][0] * scale - (1.f - (float)(ms & mt0)) * 1e12f;
            o.y = acc[i][1] * scale - (1.f - (float)(ms & mt1)) * 1e12f;
            o.z = acc[i][2] * scale - (1.f - (float)(ms & mt2)) * 1e12f;
            o.w = acc[i][3] * scale - (1.f - (float)(ms & mt3)) * 1e12f;
            *(float4*)&C[(long)(mr + i) * ldc + nc] = o;
        }
    } else if constexpr (EPI == EPI_FINAL) {
        float* C = (float*)Cout;
        const float b0 = bias[nc + 0], b1 = bias[nc + 1], b2 = bias[nc + 2], b3 = bias[nc + 3];
#pragma unroll
        for (int i = 0; i < 4; i++) {
            float4 r4 = ld4(resid + (long)(mr + i) * ldc + nc);
            float4 o;
            o.x = acc[i][0] + b0 + r4.x;
            o.y = acc[i][1] + b1 + r4.y;
            o.z = acc[i][2] + b2 + r4.z;
            o.w = acc[i][3] + b3 + r4.w;
            *(float4*)&C[(long)(mr + i) * ldc + nc] = o;
        }
    } else {
        float bj[4] = {0.f, 0.f, 0.f, 0.f};
        if constexpr (EPI == EPI_BIAS_B16 || EPI == EPI_RELU_BIAS_B16) {
#pragma unroll
            for (int j = 0; j < 4; j++) bj[j] = bias[nc + j];
        }
        unsigned short* C = (unsigned short*)Cout + (long)bz * sCb;
#pragma unroll
        for (int i = 0; i < 4; i++) {
            float c[4];
#pragma unroll
            for (int j = 0; j < 4; j++) {
                c[j] = acc[i][j] + bj[j];
                if constexpr (EPI == EPI_RELU_BIAS_B16) c[j] = fmaxf(c[j], 0.f);
            }
            ushort4 u;
            u.x = f2bu(c[0]); u.y = f2bu(c[1]); u.z = f2bu(c[2]); u.w = f2bu(c[3]);
            *(ushort4*)&C[(long)(mr + i) * ldc + nc] = u;
        }
    }
}

// one block per row; in-place masked softmax over Ss columns, then *= new_mask
__global__ __launch_bounds__(256) void softmax_rows(float* __restrict__ S,
                                                    const int* __restrict__ mask)
{
    const int row = blockIdx.x;
    const int b = row >> 10;
    const int s = row & 1023;
    float* p = S + (long)row * Ss;
    const int* mb = mask + b * Ss;
    const int t0 = threadIdx.x << 2;

    float4 v = *(float4*)&p[t0];
    __shared__ float red[256];

    float mx = fmaxf(fmaxf(v.x, v.y), fmaxf(v.z, v.w));
    red[threadIdx.x] = mx;
    __syncthreads();
    for (int off = 128; off; off >>= 1) {
        if (threadIdx.x < off) red[threadIdx.x] = fmaxf(red[threadIdx.x], red[threadIdx.x + off]);
        __syncthreads();
    }
    mx = red[0];
    __syncthreads();

    float e0 = __expf(v.x - mx), e1 = __expf(v.y - mx), e2 = __expf(v.z - mx), e3 = __expf(v.w - mx);
    red[threadIdx.x] = e0 + e1 + e2 + e3;
    __syncthreads();
    for (int off = 128; off; off >>= 1) {
        if (threadIdx.x < off) red[threadIdx.x] += red[threadIdx.x + off];
        __syncthreads();
    }
    const float inv = 1.0f / red[0];
    const float fs = (float)mb[s];

    float4 o;
    o.x = e0 * inv * fs * (float)mb[t0 + 0];
    o.y = e1 * inv * fs * (float)mb[t0 + 1];
    o.z = e2 * inv * fs * (float)mb[t0 + 2];
    o.w = e3 * inv * fs * (float)mb[t0 + 3];
    *(float4*)&p[t0] = o;
}

extern "C" void kernel_launch(void* const* d_in, const int* in_sizes, int n_in,
                              void* d_out, int out_size, void* d_ws, size_t ws_size,
                              hipStream_t stream)
{
    const float* x   = (const float*)d_in[0];
    const int* mask  = (const int*)d_in[1];
    const float* Wq  = (const float*)d_in[2];
    const float* bq  = (const float*)d_in[3];
    const float* Wk  = (const float*)d_in[4];
    const float* bk  = (const float*)d_in[5];
    const float* Wv  = (const float*)d_in[6];
    const float* bv  = (const float*)d_in[7];
    const float* W1  = (const float*)d_in[8];
    const float* b1  = (const float*)d_in[9];
    const float* W2  = (const float*)d_in[10];
    const float* b2  = (const float*)d_in[11];
    float* out = (float*)d_out;

    // workspace layout (≈193 MB):
    //   q,k,v,ctx,h1: bf16 [16384,768] each; sc: fp32 [16,1024,1024]
    bf16* q   = (bf16*)d_ws;
    bf16* k   = q + (long)MTOK * Hh;
    bf16* v   = k + (long)MTOK * Hh;
    bf16* ctx = v + (long)MTOK * Hh;
    bf16* h1  = ctx + (long)MTOK * Hh;
    float* sc = (float*)(h1 + (long)MTOK * Hh);

    const float inv_sqrt_h = 0.036084391824351615f; // 1/sqrt(768)
    dim3 blk(256);
    dim3 gProj(Hh / 64, MTOK / 64, 1);     // (12, 256)
    dim3 gScore(Ss / 64, Ss / 64, Bb);     // (16, 16, 16)
    dim3 gWV(Hh / 64, Ss / 64, Bb);        // (12, 16, 16)

    // q = relu(x Wq^T + bq), k = relu(x Wk^T + bk), v = x Wv^T + bv
    gemm_tiled<float, float, EPI_RELU_BIAS_B16, true><<<gProj, blk, 0, stream>>>(
        x, Wq, bq, nullptr, nullptr, q, MTOK, Hh, Hh, Hh, Hh, Hh, 0, 0, 0, 1.f);
    gemm_tiled<float, float, EPI_RELU_BIAS_B16, true><<<gProj, blk, 0, stream>>>(
        x, Wk, bk, nullptr, nullptr, k, MTOK, Hh, Hh, Hh, Hh, Hh, 0, 0, 0, 1.f);
    gemm_tiled<float, float, EPI_BIAS_B16, true><<<gProj, blk, 0, stream>>>(
        x, Wv, bv, nullptr, nullptr, v, MTOK, Hh, Hh, Hh, Hh, Hh, 0, 0, 0, 1.f);

    // scores = q k^T * inv_sqrt_h - (1-mm)*1e12   [B,S,S] fp32
    gemm_tiled<bf16, bf16, EPI_SCORE, true><<<gScore, blk, 0, stream>>>(
        q, k, nullptr, nullptr, mask, sc, Ss, Ss, Hh, Hh, Hh, Ss,
        (long)Ss * Hh, (long)Ss * Hh, (long)Ss * Ss, inv_sqrt_h);

    // masked softmax in-place
    softmax_rows<<<dim3(MTOK), blk, 0, stream>>>(sc, mask);

    // ctx = w v   [B,S,H] bf16
    gemm_tiled<float, bf16, EPI_B16, false><<<gWV, blk, 0, stream>>>(
        sc, v, nullptr, nullptr, nullptr, ctx, Ss, Hh, Ss, Ss, Hh, Hh,
        (long)Ss * Ss, (long)Ss * Hh, (long)Ss * Hh, 1.f);

    // h1 = relu(ctx W1^T + b1)
    gemm_tiled<bf16, float, EPI_RELU_BIAS_B16, true><<<gProj, blk, 0, stream>>>(
        ctx, W1, b1, nullptr, nullptr, h1, MTOK, Hh, Hh, Hh, Hh, Hh, 0, 0, 0, 1.f);

    // out = h1 W2^T + b2 + ctx   (fp32)
    gemm_tiled<bf16, float, EPI_FINAL, true><<<gProj, blk, 0, stream>>>(
        h1, W2, b2, ctx, nullptr, out, MTOK, Hh, Hh, Hh, Hh, Hh, 0, 0, 0, 1.f);
}

// Round 2
// 451.640 us; speedup vs baseline: 4.3636x; 4.3636x over previous
//
#include <hip/hip_runtime.h>
#include <hip/hip_bf16.h>

typedef __bf16 bf16_t;
typedef __bf16 bf16x8 __attribute__((ext_vector_type(8)));
typedef __bf16 bf16x4 __attribute__((ext_vector_type(4)));
typedef float f32x4 __attribute__((ext_vector_type(4)));
typedef unsigned int u32;
typedef const __attribute__((address_space(1))) u32* gptr_t;
typedef __attribute__((address_space(3))) u32* lptr_t;

static constexpr int Bb = 16, Ss = 1024, Hh = 768;
static constexpr int MTOK = Bb * Ss; // 16384

// ---------------- fp32 -> bf16 conversion ----------------
__global__ __launch_bounds__(256) void cvt_bf16(const float* __restrict__ in,
                                                bf16_t* __restrict__ out, int n4)
{
    int i = blockIdx.x * 256 + threadIdx.x;
    if (i < n4) {
        float4 v = ((const float4*)in)[i];
        bf16x4 o = { (bf16_t)v.x, (bf16_t)v.y, (bf16_t)v.z, (bf16_t)v.w };
        ((bf16x4*)out)[i] = o;
    }
}

// ---------------- async global->LDS 16B ----------------
__device__ __forceinline__ void async_cp16(const void* g, void* l)
{
    __builtin_amdgcn_global_load_lds((gptr_t)g, (lptr_t)l, 16, 0, 0);
}

enum { EG_RELU_BIAS_B16 = 0, EG_BIAS_VT = 1, EG_SCORE = 2, EG_B16 = 3, EG_FINAL = 4 };

// C = epi(A * B^T); A:[M,K] k-contig, B:[N,K] k-contig, bf16 inputs, fp32 accum.
// 128x128 tile, BK=32, 4 waves (2x2), mfma_f32_16x16x32_bf16 4x4 per wave.
template <int EPI>
__global__ __launch_bounds__(256) void mfma_gemm(
    const bf16_t* __restrict__ A, const bf16_t* __restrict__ B,
    const float* __restrict__ bias, const bf16_t* __restrict__ resid,
    const int* __restrict__ mask, void* __restrict__ Cout,
    int K, int lda, int ldb, int ldc,
    long sA, long sB, long sC, float scale)
{
    __shared__ bf16_t Asl[128 * 32];
    __shared__ bf16_t Bsl[128 * 32];

    const int tid = threadIdx.x;
    const int wid = tid >> 6;
    const int lane = tid & 63;
    const int wm = wid & 1, wn = wid >> 1;
    const int m0 = blockIdx.y * 128;
    const int n0 = blockIdx.x * 128;
    const int bz = blockIdx.z;

    const bf16_t* Ab = A + (long)bz * sA;
    const bf16_t* Bp = B + (long)bz * sB;

    // staging: each thread loads 16B; wave w covers 16 rows per 64-row half
    const int srow = (wid << 4) + (lane >> 2);   // 0..63
    const int scol = (lane & 3) << 3;            // element offset 0,8,16,24

    const bf16_t* pa0 = Ab + (long)(m0 + srow) * lda + scol;
    const bf16_t* pa1 = Ab + (long)(m0 + 64 + srow) * lda + scol;
    const bf16_t* pb0 = Bp + (long)(n0 + srow) * ldb + scol;
    const bf16_t* pb1 = Bp + (long)(n0 + 64 + srow) * ldb + scol;

    bf16_t* la = &Asl[(wid << 4) * 32];          // wave-uniform LDS bases
    bf16_t* lb = &Bsl[(wid << 4) * 32];

    const int row16 = lane & 15;
    const int kq = (lane >> 4) << 3;

    f32x4 acc[4][4] = {};

    for (int k0 = 0; k0 < K; k0 += 32) {
        async_cp16(pa0 + k0, la);
        async_cp16(pa1 + k0, la + 64 * 32);
        async_cp16(pb0 + k0, lb);
        async_cp16(pb1 + k0, lb + 64 * 32);
        __syncthreads();

        bf16x8 af[4], bfr[4];
#pragma unroll
        for (int i = 0; i < 4; i++)
            af[i] = *(const bf16x8*)&Asl[((wm << 6) + (i << 4) + row16) * 32 + kq];
#pragma unroll
        for (int j = 0; j < 4; j++)
            bfr[j] = *(const bf16x8*)&Bsl[((wn << 6) + (j << 4) + row16) * 32 + kq];
#pragma unroll
        for (int i = 0; i < 4; i++)
#pragma unroll
            for (int j = 0; j < 4; j++)
                acc[i][j] = __builtin_amdgcn_mfma_f32_16x16x32_bf16(af[i], bfr[j], acc[i][j], 0, 0, 0);
        __syncthreads();
    }

    // epilogue — C/D layout per 16x16 tile: col = lane&15, row = (lane>>4)*4 + reg
    const int mb_ = m0 + (wm << 6);
    const int nb_ = n0 + (wn << 6);
    const int colw = lane & 15;
    const int rowq = (lane >> 4) << 2;

    if constexpr (EPI == EG_SCORE) {
        float* C = (float*)Cout + (long)bz * sC;
        const int* mk = mask + bz * Ss;
        int mt[4], ms[4][4];
#pragma unroll
        for (int j = 0; j < 4; j++) mt[j] = mk[nb_ + (j << 4) + colw];
#pragma unroll
        for (int i = 0; i < 4; i++)
#pragma unroll
            for (int r = 0; r < 4; r++) ms[i][r] = mk[mb_ + (i << 4) + rowq + r];
#pragma unroll
        for (int i = 0; i < 4; i++)
#pragma unroll
            for (int j = 0; j < 4; j++)
#pragma unroll
                for (int r = 0; r < 4; r++) {
                    int row = mb_ + (i << 4) + rowq + r;
                    int col = nb_ + (j << 4) + colw;
                    float pen = (1.f - (float)(ms[i][r] & mt[j])) * 1e12f;
                    C[(long)row * ldc + col] = acc[i][j][r] * scale - pen;
                }
    } else if constexpr (EPI == EG_BIAS_VT) {
        // write V transposed: vT[b][h][s], 4 consecutive s per reg quad -> bf16x4 store
        bf16_t* C = (bf16_t*)Cout;
        float bj[4];
#pragma unroll
        for (int j = 0; j < 4; j++) bj[j] = bias[nb_ + (j << 4) + colw];
#pragma unroll
        for (int i = 0; i < 4; i++) {
            const int sAbs = mb_ + (i << 4) + rowq;  // global token, 4-aligned
            const int b = sAbs >> 10;
            const int sl = sAbs & 1023;
#pragma unroll
            for (int j = 0; j < 4; j++) {
                const int col = nb_ + (j << 4) + colw;
                bf16x4 o = { (bf16_t)(acc[i][j][0] + bj[j]), (bf16_t)(acc[i][j][1] + bj[j]),
                             (bf16_t)(acc[i][j][2] + bj[j]), (bf16_t)(acc[i][j][3] + bj[j]) };
                *(bf16x4*)&C[((long)b * Hh + col) * Ss + sl] = o;
            }
        }
    } else if constexpr (EPI == EG_FINAL) {
        float* C = (float*)Cout;
        float bj[4];
#pragma unroll
        for (int j = 0; j < 4; j++) bj[j] = bias[nb_ + (j << 4) + colw];
#pragma unroll
        for (int i = 0; i < 4; i++)
#pragma unroll
            for (int j = 0; j < 4; j++)
#pragma unroll
                for (int r = 0; r < 4; r++) {
                    int row = mb_ + (i << 4) + rowq + r;
                    int col = nb_ + (j << 4) + colw;
                    C[(long)row * ldc + col] =
                        acc[i][j][r] + bj[j] + (float)resid[(long)row * ldc + col];
                }
    } else {
        // EG_RELU_BIAS_B16 / EG_B16 -> bf16 output
        bf16_t* C = (bf16_t*)Cout + (long)bz * sC;
        float bj[4] = {0.f, 0.f, 0.f, 0.f};
        if constexpr (EPI == EG_RELU_BIAS_B16) {
#pragma unroll
            for (int j = 0; j < 4; j++) bj[j] = bias[nb_ + (j << 4) + colw];
        }
#pragma unroll
        for (int i = 0; i < 4; i++)
#pragma unroll
            for (int j = 0; j < 4; j++)
#pragma unroll
                for (int r = 0; r < 4; r++) {
                    int row = mb_ + (i << 4) + rowq + r;
                    int col = nb_ + (j << 4) + colw;
                    float v = acc[i][j][r] + bj[j];
                    if constexpr (EPI == EG_RELU_BIAS_B16) v = fmaxf(v, 0.f);
                    C[(long)row * ldc + col] = (bf16_t)v;
                }
    }
}

// ---------------- masked softmax, fp32 in / bf16 out (in place) ----------------
__global__ __launch_bounds__(256) void softmax_rows(float* __restrict__ S_,
                                                    const int* __restrict__ mask)
{
    const int row = blockIdx.x;
    const int b = row >> 10;
    const int s = row & 1023;
    float* p = S_ + (long)row * Ss;
    const int* mk = mask + b * Ss;
    const int t = threadIdx.x;
    const int t0 = t << 2;

    float4 v = *(const float4*)&p[t0];

    float mx = fmaxf(fmaxf(v.x, v.y), fmaxf(v.z, v.w));
#pragma unroll
    for (int off = 32; off; off >>= 1) mx = fmaxf(mx, __shfl_down(mx, off, 64));
    __shared__ float redm[4], reds[4];
    if ((t & 63) == 0) redm[t >> 6] = mx;
    __syncthreads();
    mx = fmaxf(fmaxf(redm[0], redm[1]), fmaxf(redm[2], redm[3]));

    float e0 = __expf(v.x - mx), e1 = __expf(v.y - mx);
    float e2 = __expf(v.z - mx), e3 = __expf(v.w - mx);
    float sm = e0 + e1 + e2 + e3;
#pragma unroll
    for (int off = 32; off; off >>= 1) sm += __shfl_down(sm, off, 64);
    if ((t & 63) == 0) reds[t >> 6] = sm;
    __syncthreads();
    sm = reds[0] + reds[1] + reds[2] + reds[3];

    const float inv = 1.f / sm;
    const float fs = (float)mk[s];
    bf16x4 o = { (bf16_t)(e0 * inv * fs * (float)mk[t0 + 0]),
                 (bf16_t)(e1 * inv * fs * (float)mk[t0 + 1]),
                 (bf16_t)(e2 * inv * fs * (float)mk[t0 + 2]),
                 (bf16_t)(e3 * inv * fs * (float)mk[t0 + 3]) };
    // all reads of this row completed before the barriers above; safe to overlay
    ((bf16x4*)p)[t] = o;
}

extern "C" void kernel_launch(void* const* d_in, const int* in_sizes, int n_in,
                              void* d_out, int out_size, void* d_ws, size_t ws_size,
                              hipStream_t stream)
{
    const float* x  = (const float*)d_in[0];
    const int* mask = (const int*)d_in[1];
    const float* Wq = (const float*)d_in[2];
    const float* bq = (const float*)d_in[3];
    const float* Wk = (const float*)d_in[4];
    const float* bk = (const float*)d_in[5];
    const float* Wv = (const float*)d_in[6];
    const float* bv = (const float*)d_in[7];
    const float* W1 = (const float*)d_in[8];
    const float* b1 = (const float*)d_in[9];
    const float* W2 = (const float*)d_in[10];
    const float* b2 = (const float*)d_in[11];
    float* out = (float*)d_out;

    // workspace layout (~174 MB)
    char* w = (char*)d_ws;
    bf16_t* xb  = (bf16_t*)(w + 0);           // [16384,768] bf16, reused as ctx
    bf16_t* qb  = (bf16_t*)(w + 25165824);    // reused as h1
    bf16_t* kb  = (bf16_t*)(w + 50331648);
    bf16_t* vT  = (bf16_t*)(w + 75497472);    // [16,768,1024] bf16
    float*  sc  = (float*) (w + 100663296);   // [16,1024,1024] fp32; bf16 wb overlaid
    bf16_t* wqb = (bf16_t*)(w + 167772160);
    bf16_t* wkb = wqb + 589824;
    bf16_t* wvb = wkb + 589824;
    bf16_t* w1b = wvb + 589824;
    bf16_t* w2b = w1b + 589824;
    bf16_t* ctx = xb;
    bf16_t* h1  = qb;
    bf16_t* wb  = (bf16_t*)sc;

    const float inv_sqrt_h = 0.036084391824351615f; // 1/sqrt(768)

    cvt_bf16<<<12288, 256, 0, stream>>>(x, xb, 3145728);
    cvt_bf16<<<576, 256, 0, stream>>>(Wq, wqb, 147456);
    cvt_bf16<<<576, 256, 0, stream>>>(Wk, wkb, 147456);
    cvt_bf16<<<576, 256, 0, stream>>>(Wv, wvb, 147456);
    cvt_bf16<<<576, 256, 0, stream>>>(W1, w1b, 147456);
    cvt_bf16<<<576, 256, 0, stream>>>(W2, w2b, 147456);

    dim3 blk(256);
    dim3 gProj(6, 128, 1);   // N=768, M=16384
    dim3 gScore(8, 8, 16);   // N=1024, M=1024, B=16
    dim3 gPV(6, 8, 16);      // N=768,  M=1024, B=16

    // q = relu(x Wq^T + bq)  [bf16]
    mfma_gemm<EG_RELU_BIAS_B16><<<gProj, blk, 0, stream>>>(
        xb, wqb, bq, nullptr, nullptr, qb, 768, 768, 768, 768, 0, 0, 0, 1.f);
    // k = relu(x Wk^T + bk)  [bf16]
    mfma_gemm<EG_RELU_BIAS_B16><<<gProj, blk, 0, stream>>>(
        xb, wkb, bk, nullptr, nullptr, kb, 768, 768, 768, 768, 0, 0, 0, 1.f);
    // vT[b][h][s] = (x Wv^T + bv)^T  [bf16]
    mfma_gemm<EG_BIAS_VT><<<gProj, blk, 0, stream>>>(
        xb, wvb, bv, nullptr, nullptr, vT, 768, 768, 768, 0, 0, 0, 0, 1.f);
    // sc = q k^T * inv_sqrt_h - (1-mm)*1e12  [fp32]
    mfma_gemm<EG_SCORE><<<gScore, blk, 0, stream>>>(
        qb, kb, nullptr, nullptr, mask, sc, 768, 768, 768, 1024,
        786432, 786432, 1048576, inv_sqrt_h);
    // softmax rows -> bf16 wb (overlaid on sc)
    softmax_rows<<<dim3(MTOK), blk, 0, stream>>>(sc, mask);
    // ctx = wb vT^T  [bf16]   (A: lda=2048 bf16 elems over fp32 rows)
    mfma_gemm<EG_B16><<<gPV, blk, 0, stream>>>(
        wb, vT, nullptr, nullptr, nullptr, ctx, 1024, 2048, 1024, 768,
        2097152, 786432, 786432, 1.f);
    // h1 = relu(ctx W1^T + b1)  [bf16]
    mfma_gemm<EG_RELU_BIAS_B16><<<gProj, blk, 0, stream>>>(
        ctx, w1b, b1, nullptr, nullptr, h1, 768, 768, 768, 768, 0, 0, 0, 1.f);
    // out = h1 W2^T + b2 + ctx  [fp32]
    mfma_gemm<EG_FINAL><<<gProj, blk, 0, stream>>>(
        h1, w2b, b2, ctx, nullptr, out, 768, 768, 768, 768, 0, 0, 0, 1.f);
}

// Round 3
// 417.491 us; speedup vs baseline: 4.7205x; 1.0818x over previous
//
#include <hip/hip_runtime.h>
#include <hip/hip_bf16.h>

typedef __bf16 bf16_t;
typedef __bf16 bf16x8 __attribute__((ext_vector_type(8)));
typedef __bf16 bf16x4 __attribute__((ext_vector_type(4)));
typedef float f32x4 __attribute__((ext_vector_type(4)));
typedef unsigned int u32;
typedef const __attribute__((address_space(1))) u32* gptr_t;
typedef __attribute__((address_space(3))) u32* lptr_t;

static constexpr int Bb = 16, Ss = 1024, Hh = 768;
static constexpr int MTOK = Bb * Ss; // 16384

// ---------------- fp32 -> bf16 conversion (x) ----------------
__global__ __launch_bounds__(256) void cvt_bf16(const float* __restrict__ in,
                                                bf16_t* __restrict__ out, int n4)
{
    int i = blockIdx.x * 256 + threadIdx.x;
    if (i < n4) {
        float4 v = ((const float4*)in)[i];
        bf16x4 o = { (bf16_t)v.x, (bf16_t)v.y, (bf16_t)v.z, (bf16_t)v.w };
        ((bf16x4*)out)[i] = o;
    }
}

// ---- all 5 weights -> one contiguous bf16 slab [Wq|Wk|Wv|W1|W2]; pack bqkv ----
__global__ __launch_bounds__(256) void cvt_w(
    const float* __restrict__ w0, const float* __restrict__ w1,
    const float* __restrict__ w2, const float* __restrict__ w3,
    const float* __restrict__ w4,
    const float* __restrict__ bq, const float* __restrict__ bk,
    const float* __restrict__ bv,
    bf16_t* __restrict__ wdst, float* __restrict__ bdst)
{
    int bx = blockIdx.x;
    if (bx < 2880) {
        int seg = bx / 576;
        const float* src = seg == 0 ? w0 : seg == 1 ? w1 : seg == 2 ? w2 : seg == 3 ? w3 : w4;
        int i = (bx % 576) * 256 + threadIdx.x;   // float4 index, 576*256 == 147456 exact
        float4 v = ((const float4*)src)[i];
        bf16x4 o = { (bf16_t)v.x, (bf16_t)v.y, (bf16_t)v.z, (bf16_t)v.w };
        ((bf16x4*)(wdst + (long)seg * 589824))[i] = o;
    } else {
        int i = (bx - 2880) * 256 + threadIdx.x;
        if (i < 2304)
            bdst[i] = i < 768 ? bq[i] : i < 1536 ? bk[i - 768] : bv[i - 1536];
    }
}

// ---------------- async global->LDS 16B ----------------
__device__ __forceinline__ void async_cp16(const void* g, void* l)
{
    __builtin_amdgcn_global_load_lds((gptr_t)g, (lptr_t)l, 16, 0, 0);
}

enum { EG_RELU_BIAS_B16 = 0, EG_QKV = 1, EG_SCORE_T = 2, EG_B16 = 3, EG_FINAL = 4 };

// C = epi(A * B^T); A:[M,K] k-contig, B:[N,K] k-contig, bf16 inputs, fp32 accum.
// 128x128 tile, BK=32, 4 waves (2x2), mfma_f32_16x16x32_bf16 4x4 per wave.
template <int EPI>
__global__ __launch_bounds__(256) void mfma_gemm(
    const bf16_t* __restrict__ A, const bf16_t* __restrict__ B,
    const float* __restrict__ bias, const bf16_t* __restrict__ resid,
    const int* __restrict__ mask, void* __restrict__ Cout,
    bf16_t* __restrict__ out2, bf16_t* __restrict__ out3,
    int K, int lda, int ldb, int ldc,
    long sA, long sB, long sC, float scale)
{
    __shared__ bf16_t Asl[128 * 32];
    __shared__ bf16_t Bsl[128 * 32];

    const int tid = threadIdx.x;
    const int wid = tid >> 6;
    const int lane = tid & 63;
    const int wm = wid & 1, wn = wid >> 1;
    const int m0 = blockIdx.y * 128;
    const int n0 = blockIdx.x * 128;
    const int bz = blockIdx.z;

    const bf16_t* Ab = A + (long)bz * sA;
    const bf16_t* Bp = B + (long)bz * sB;

    const int srow = (wid << 4) + (lane >> 2);   // 0..63
    const int scol = (lane & 3) << 3;            // 0,8,16,24

    const bf16_t* pa0 = Ab + (long)(m0 + srow) * lda + scol;
    const bf16_t* pa1 = Ab + (long)(m0 + 64 + srow) * lda + scol;
    const bf16_t* pb0 = Bp + (long)(n0 + srow) * ldb + scol;
    const bf16_t* pb1 = Bp + (long)(n0 + 64 + srow) * ldb + scol;

    bf16_t* la = &Asl[(wid << 4) * 32];
    bf16_t* lb = &Bsl[(wid << 4) * 32];

    const int row16 = lane & 15;
    const int kq = (lane >> 4) << 3;

    f32x4 acc[4][4] = {};

    for (int k0 = 0; k0 < K; k0 += 32) {
        async_cp16(pa0 + k0, la);
        async_cp16(pa1 + k0, la + 64 * 32);
        async_cp16(pb0 + k0, lb);
        async_cp16(pb1 + k0, lb + 64 * 32);
        __syncthreads();

        bf16x8 af[4], bfr[4];
#pragma unroll
        for (int i = 0; i < 4; i++)
            af[i] = *(const bf16x8*)&Asl[((wm << 6) + (i << 4) + row16) * 32 + kq];
#pragma unroll
        for (int j = 0; j < 4; j++)
            bfr[j] = *(const bf16x8*)&Bsl[((wn << 6) + (j << 4) + row16) * 32 + kq];
#pragma unroll
        for (int i = 0; i < 4; i++)
#pragma unroll
            for (int j = 0; j < 4; j++)
                acc[i][j] = __builtin_amdgcn_mfma_f32_16x16x32_bf16(af[i], bfr[j], acc[i][j], 0, 0, 0);
        __syncthreads();
    }

    // epilogue — C/D layout per 16x16 tile: col = lane&15, row = (lane>>4)*4 + reg
    const int mb_ = m0 + (wm << 6);
    const int nb_ = n0 + (wn << 6);
    const int colw = lane & 15;
    const int rowq = (lane >> 4) << 2;

    if constexpr (EPI == EG_QKV) {
        // cols 0..767 -> q (relu+bias), 768..1535 -> k (relu+bias), 1536..2303 -> vT
        float bj[4];
#pragma unroll
        for (int j = 0; j < 4; j++) bj[j] = bias[nb_ + (j << 4) + colw];
        if (nb_ < 1536) {
            bf16_t* C = (nb_ < 768) ? (bf16_t*)Cout : out2;
            const int cb = (nb_ < 768) ? nb_ : nb_ - 768;
#pragma unroll
            for (int i = 0; i < 4; i++)
#pragma unroll
                for (int j = 0; j < 4; j++)
#pragma unroll
                    for (int r = 0; r < 4; r++) {
                        int row = mb_ + (i << 4) + rowq + r;
                        int col = cb + (j << 4) + colw;
                        float v = fmaxf(acc[i][j][r] + bj[j], 0.f);
                        C[(long)row * Hh + col] = (bf16_t)v;
                    }
        } else {
#pragma unroll
            for (int i = 0; i < 4; i++) {
                const int sAbs = mb_ + (i << 4) + rowq;
                const int b = sAbs >> 10;
                const int sl = sAbs & 1023;
#pragma unroll
                for (int j = 0; j < 4; j++) {
                    const int col = nb_ - 1536 + (j << 4) + colw;
                    bf16x4 o = { (bf16_t)(acc[i][j][0] + bj[j]), (bf16_t)(acc[i][j][1] + bj[j]),
                                 (bf16_t)(acc[i][j][2] + bj[j]), (bf16_t)(acc[i][j][3] + bj[j]) };
                    *(bf16x4*)&out3[((long)b * Hh + col) * Ss + sl] = o;
                }
            }
        }
    } else if constexpr (EPI == EG_SCORE_T) {
        // computed T = k·q^T; store S = T^T as bf16 with mask penalty.
        // acc rows = keys (i_), cols = queries (j_); S[j_][i_] gets 4 consecutive keys.
        bf16_t* C = (bf16_t*)Cout + (long)bz * sC;
        const int* mk = mask + bz * Ss;
        int mq[4], mkk[4][4];
#pragma unroll
        for (int j = 0; j < 4; j++) mq[j] = mk[nb_ + (j << 4) + colw];
#pragma unroll
        for (int i = 0; i < 4; i++)
#pragma unroll
            for (int r = 0; r < 4; r++) mkk[i][r] = mk[mb_ + (i << 4) + rowq + r];
#pragma unroll
        for (int i = 0; i < 4; i++) {
            const int kbase = mb_ + (i << 4) + rowq;
#pragma unroll
            for (int j = 0; j < 4; j++) {
                const int qrow = nb_ + (j << 4) + colw;
                bf16x4 o;
#pragma unroll
                for (int r = 0; r < 4; r++) {
                    float pen = (1.f - (float)(mkk[i][r] & mq[j])) * 1e12f;
                    o[r] = (bf16_t)(acc[i][j][r] * scale - pen);
                }
                *(bf16x4*)&C[(long)qrow * ldc + kbase] = o;
            }
        }
    } else if constexpr (EPI == EG_FINAL) {
        float* C = (float*)Cout;
        float bj[4];
#pragma unroll
        for (int j = 0; j < 4; j++) bj[j] = bias[nb_ + (j << 4) + colw];
#pragma unroll
        for (int i = 0; i < 4; i++)
#pragma unroll
            for (int j = 0; j < 4; j++)
#pragma unroll
                for (int r = 0; r < 4; r++) {
                    int row = mb_ + (i << 4) + rowq + r;
                    int col = nb_ + (j << 4) + colw;
                    C[(long)row * ldc + col] =
                        acc[i][j][r] + bj[j] + (float)resid[(long)row * ldc + col];
                }
    } else {
        // EG_RELU_BIAS_B16 / EG_B16 -> bf16 output
        bf16_t* C = (bf16_t*)Cout + (long)bz * sC;
        float bj[4] = {0.f, 0.f, 0.f, 0.f};
        if constexpr (EPI == EG_RELU_BIAS_B16) {
#pragma unroll
            for (int j = 0; j < 4; j++) bj[j] = bias[nb_ + (j << 4) + colw];
        }
#pragma unroll
        for (int i = 0; i < 4; i++)
#pragma unroll
            for (int j = 0; j < 4; j++)
#pragma unroll
                for (int r = 0; r < 4; r++) {
                    int row = mb_ + (i << 4) + rowq + r;
                    int col = nb_ + (j << 4) + colw;
                    float v = acc[i][j][r] + bj[j];
                    if constexpr (EPI == EG_RELU_BIAS_B16) v = fmaxf(v, 0.f);
                    C[(long)row * ldc + col] = (bf16_t)v;
                }
    }
}

// ---------------- masked softmax, bf16 in / bf16 out (in place) ----------------
__global__ __launch_bounds__(256) void softmax_rows(bf16_t* __restrict__ S_,
                                                    const int* __restrict__ mask)
{
    const int row = blockIdx.x;
    const int b = row >> 10;
    const int s = row & 1023;
    bf16_t* p = S_ + (long)row * Ss;
    const int* mk = mask + b * Ss;
    const int t = threadIdx.x;
    const int t0 = t << 2;

    bf16x4 v4 = *(const bf16x4*)&p[t0];
    float v0 = (float)v4[0], v1 = (float)v4[1], v2 = (float)v4[2], v3 = (float)v4[3];

    float mx = fmaxf(fmaxf(v0, v1), fmaxf(v2, v3));
#pragma unroll
    for (int off = 32; off; off >>= 1) mx = fmaxf(mx, __shfl_down(mx, off, 64));
    __shared__ float redm[4], reds[4];
    if ((t & 63) == 0) redm[t >> 6] = mx;
    __syncthreads();
    mx = fmaxf(fmaxf(redm[0], redm[1]), fmaxf(redm[2], redm[3]));

    float e0 = __expf(v0 - mx), e1 = __expf(v1 - mx);
    float e2 = __expf(v2 - mx), e3 = __expf(v3 - mx);
    float sm = e0 + e1 + e2 + e3;
#pragma unroll
    for (int off = 32; off; off >>= 1) sm += __shfl_down(sm, off, 64);
    if ((t & 63) == 0) reds[t >> 6] = sm;
    __syncthreads();
    sm = reds[0] + reds[1] + reds[2] + reds[3];

    const float inv = 1.f / sm;
    const float fs = (float)mk[s];
    bf16x4 o = { (bf16_t)(e0 * inv * fs * (float)mk[t0 + 0]),
                 (bf16_t)(e1 * inv * fs * (float)mk[t0 + 1]),
                 (bf16_t)(e2 * inv * fs * (float)mk[t0 + 2]),
                 (bf16_t)(e3 * inv * fs * (float)mk[t0 + 3]) };
    *(bf16x4*)&p[t0] = o;
}

extern "C" void kernel_launch(void* const* d_in, const int* in_sizes, int n_in,
                              void* d_out, int out_size, void* d_ws, size_t ws_size,
                              hipStream_t stream)
{
    const float* x  = (const float*)d_in[0];
    const int* mask = (const int*)d_in[1];
    const float* Wq = (const float*)d_in[2];
    const float* bq = (const float*)d_in[3];
    const float* Wk = (const float*)d_in[4];
    const float* bk = (const float*)d_in[5];
    const float* Wv = (const float*)d_in[6];
    const float* bv = (const float*)d_in[7];
    const float* W1 = (const float*)d_in[8];
    const float* b1 = (const float*)d_in[9];
    const float* W2 = (const float*)d_in[10];
    const float* b2 = (const float*)d_in[11];
    float* out = (float*)d_out;

    // workspace layout (~140 MB)
    char* w = (char*)d_ws;
    bf16_t* xb   = (bf16_t*)(w + 0);            // [16384,768], reused as ctx
    bf16_t* qb   = (bf16_t*)(w + 25165824);     // reused as h1
    bf16_t* kb   = (bf16_t*)(w + 50331648);
    bf16_t* vT   = (bf16_t*)(w + 75497472);     // [16,768,1024]
    bf16_t* sc   = (bf16_t*)(w + 100663296);    // [16,1024,1024] bf16
    bf16_t* wqkv = (bf16_t*)(w + 134217728);    // [2304,768] = Wq|Wk|Wv
    bf16_t* w1b  = (bf16_t*)(w + 137756672);
    bf16_t* w2b  = (bf16_t*)(w + 138936320);
    float*  bqkv = (float*) (w + 140115968);    // [2304]
    bf16_t* ctx  = xb;
    bf16_t* h1   = qb;

    const float inv_sqrt_h = 0.036084391824351615f; // 1/sqrt(768)

    cvt_bf16<<<12288, 256, 0, stream>>>(x, xb, 3145728);
    cvt_w<<<2883, 256, 0, stream>>>(Wq, Wk, Wv, W1, W2, bq, bk, bv, wqkv, bqkv);

    dim3 blk(256);

    // fused q|k|vT = epi(x · [Wq|Wk|Wv]^T + bqkv)
    mfma_gemm<EG_QKV><<<dim3(18, 128, 1), blk, 0, stream>>>(
        xb, wqkv, bqkv, nullptr, nullptr, qb, kb, vT,
        768, 768, 768, 768, 0, 0, 0, 1.f);

    // sc[q][k] = (k·q^T)^T * scale - pen, bf16
    mfma_gemm<EG_SCORE_T><<<dim3(8, 8, 16), blk, 0, stream>>>(
        kb, qb, nullptr, nullptr, mask, sc, nullptr, nullptr,
        768, 768, 768, 1024, 786432, 786432, 1048576, inv_sqrt_h);

    // masked softmax in place (bf16)
    softmax_rows<<<dim3(MTOK), blk, 0, stream>>>(sc, mask);

    // ctx = sc · vT^T
    mfma_gemm<EG_B16><<<dim3(6, 8, 16), blk, 0, stream>>>(
        sc, vT, nullptr, nullptr, nullptr, ctx, nullptr, nullptr,
        1024, 1024, 1024, 768, 1048576, 786432, 786432, 1.f);

    // h1 = relu(ctx · W1^T + b1)
    mfma_gemm<EG_RELU_BIAS_B16><<<dim3(6, 128, 1), blk, 0, stream>>>(
        ctx, w1b, b1, nullptr, nullptr, h1, nullptr, nullptr,
        768, 768, 768, 768, 0, 0, 0, 1.f);

    // out = h1 · W2^T + b2 + ctx  (fp32)
    mfma_gemm<EG_FINAL><<<dim3(6, 128, 1), blk, 0, stream>>>(
        h1, w2b, b2, ctx, nullptr, out, nullptr, nullptr,
        768, 768, 768, 768, 0, 0, 0, 1.f);
}